// Round 19
// baseline (614.701 us; speedup 1.0000x reference)
//
#include <hip/hip_runtime.h>
#include <stdint.h>

#define FPOFF _Pragma("clang fp contract(off)")

// ---------------- problem sizes ----------------
#define ROWS 8192      // N*Ho*Wo = 8*32*32
#define OC 128
#define NS 5           // subarrays
#define SUB 128
#define LP 640         // NS*SUB (padded L)
#define LREAL 576      // C*kh*kw = 64*9
#define NZ 7           // activation bits
#define NK 3           // weight cells
#define NSLOT 21
#define NPTOT 245760   // 3*128*5*128   probs element count
#define NNTOT 1720320  // 7*3*128*5*128 noise element count
#define PARTSZ 5242880 // NS*OC*ROWS floats (one partial buffer, [s][o][r])

// prep-A plane bases (1D grid): [0,128)=xmax, [128,288)=wq(160), [288,1248)=cls
// (init is a SEPARATE launch: its plain hdr stores must be ordered before
//  xmax's atomicMax on hdr[0] — fusing them raced across graph replays, r17)
#define A_WQ   128
#define A_CLS  288
#define A_NB   1248
// prep-C plane bases: [0,640)=pack, [640,7360)=rq
#define C_RQ   640
#define C_NB   7360

// ---------------- ws layout (bytes) ----------------
#define OFF_HDR      0u          // u32[64]: [0]=xmax_enc, pmin[21]@idx8, pmax[21]@idx32
#define OFF_WSCALE   256u        // f32 [NS][OC]
#define OFF_WQ       4096u       // i8  [OC][LP]
#define OFF_CLS      86016u      // u8  [NK][OC][NS][SUB]
#define OFF_INPUTQ   331776u     // u8  [ROWS][LP]
#define OFF_PACKB    5574656u    // u32 [NZ][ROWS][NS][4]
#define OFF_RQ       10162176u   // f32 [NZ][NK][NS][SUB][OC]
#define OFF_PARTS    17043456u   // f32 [6][PARTSZ]  (A=0..2 z even, B=3..5 z odd; 126 MB)
#define OFF_OUTACC   142872576u  // f32 [ROWS*OC] keyed by o-major e  (ends ~147 MB)

struct U2 { uint32_t x, y; };

__host__ __device__ static inline uint32_t rotl32(uint32_t v, int d){ return (v << d) | (v >> (32 - d)); }

// JAX threefry2x32: 20 rounds, injection every 4. keys (k0,k1), counter (c0,c1).
__host__ __device__ static inline U2 threefry(uint32_t k0, uint32_t k1, uint32_t c0, uint32_t c1){
  uint32_t ks2 = k0 ^ k1 ^ 0x1BD11BDAu;
  uint32_t x0 = c0 + k0, x1 = c1 + k1;
#define TFR(r) { x0 += x1; x1 = rotl32(x1, r); x1 ^= x0; }
  TFR(13) TFR(15) TFR(26) TFR(6)  x0 += k1;  x1 += ks2 + 1u;
  TFR(17) TFR(29) TFR(16) TFR(24) x0 += ks2; x1 += k0 + 2u;
  TFR(13) TFR(15) TFR(26) TFR(6)  x0 += k0;  x1 += k1 + 3u;
  TFR(17) TFR(29) TFR(16) TFR(24) x0 += k1;  x1 += ks2 + 4u;
  TFR(13) TFR(15) TFR(26) TFR(6)  x0 += ks2; x1 += k0 + 5u;
#undef TFR
  U2 r; r.x = x0; r.y = x1; return r;
}

__device__ static inline float u2f(uint32_t b){
  // JAX uniform [0,1): bitcast((bits>>9)|0x3f800000) - 1
  return __uint_as_float((b >> 9) | 0x3F800000u) - 1.0f;
}

// order-preserving float<->uint encode for atomic min/max
__device__ static inline uint32_t encf(float f){
  uint32_t u = __float_as_uint(f);
  return (u & 0x80000000u) ? ~u : (u | 0x80000000u);
}
__device__ static inline float decf(uint32_t e){
  return (e & 0x80000000u) ? __uint_as_float(e & 0x7FFFFFFFu) : __uint_as_float(~e);
}

// XLA/chlo erf_inv f32 (Giles). log1p/sqrt via f64 for correctly-rounded f32.
__device__ static inline float xla_erfinv(float x){
  FPOFF
  float m = x * x;
  float w = -(float)log1p((double)(-m));
  float p;
  if (w < 5.0f){
    w = w - 2.5f;
    p = 2.81022636e-08f;
    p = 3.43273939e-07f  + p * w;
    p = -3.5233877e-06f  + p * w;
    p = -4.39150654e-06f + p * w;
    p = 0.00021858087f   + p * w;
    p = -0.00125372503f  + p * w;
    p = -0.00417768164f  + p * w;
    p = 0.246640727f     + p * w;
    p = 1.50140941f      + p * w;
  } else {
    w = (float)sqrt((double)w) - 3.0f;
    p = -0.000200214257f;
    p = 0.000100950558f  + p * w;
    p = 0.00134934322f   + p * w;
    p = -0.00367342844f  + p * w;
    p = 0.00573950773f   + p * w;
    p = -0.0076224613f   + p * w;
    p = 0.00943887047f   + p * w;
    p = 1.00167406f      + p * w;
    p = 2.83297682f      + p * w;
  }
  return p * x;
}

// ---------------- kernels ----------------

// separate launch: must complete before prepA's xmax atomics touch hdr[0]
__global__ void k_init(uint32_t* hdr){
  int t = threadIdx.x;
  if (t == 0) hdr[0] = 0u;
  if (t < NSLOT){ hdr[8 + t] = 0xFFFFFFFFu; hdr[32 + t] = 0u; }
}

// ---------------- fused prep A: xmax | wq | cls ----------------
// All three are mutually independent; disjoint 1D block ranges; bodies verbatim.
__global__ void k_prepA(const float* __restrict__ x, const float* __restrict__ wt,
                        uint32_t* __restrict__ hdr, float* __restrict__ wscale,
                        int8_t* __restrict__ wq, uint8_t* __restrict__ cls,
                        uint32_t km0, uint32_t km1){
  FPOFF
  __shared__ float red[4];
  const int b = blockIdx.x;
  const int t = threadIdx.x;
  if (b < A_WQ){
    // ---- xmax block (verbatim) ----
    const float4* x4 = (const float4*)x;
    int base = b * 1024 + t;
    float m = 0.0f;
#pragma unroll
    for (int i = 0; i < 4; ++i){
      float4 v = x4[base + i * 256];
      m = fmaxf(m, fmaxf(fmaxf(v.x, v.y), fmaxf(v.z, v.w)));
    }
    for (int off = 32; off; off >>= 1) m = fmaxf(m, __shfl_down(m, off));
    if ((t & 63) == 0) red[t >> 6] = m;
    __syncthreads();
    if (t == 0){
      m = fmaxf(fmaxf(red[0], red[1]), fmaxf(red[2], red[3]));
      atomicMax(&hdr[0], encf(m));
    }
  } else if (b < A_CLS){
    // ---- wq: 4 (s,o) pairs per block, one per wave (shuffles are wave-local) ----
    const int p = (b - A_WQ) * 4 + (t >> 6);   // 0..639
    const int s = p >> 7, o = p & 127;
    const int lane = t & 63;
    int l0 = s * SUB + lane, l1 = l0 + 64;
    float w0 = (l0 < LREAL) ? wt[o * LREAL + l0] : 0.f;
    float w1 = (l1 < LREAL) ? wt[o * LREAL + l1] : 0.f;
    float m = fmaxf(fabsf(w0), fabsf(w1));
    for (int off = 32; off; off >>= 1) m = fmaxf(m, __shfl_down(m, off));
    m = __shfl(m, 0);
    float ws = fmaxf(m, 1e-8f) / 127.0f;
    if (lane == 0) wscale[s * OC + o] = ws;
    wq[o * LP + l0] = (int8_t)(int)rintf(w0 / ws);
    wq[o * LP + l1] = (int8_t)(int)rintf(w1 / ws);
  } else {
    // ---- cls (verbatim) ----
    int i = (b - A_CLS) * 256 + t;
    if (i < NPTOT){
      U2 r = threefry(km0, km1, 0u, (uint32_t)i);
      float f = u2f(r.x ^ r.y);
      cls[i] = (f < 0.001f) ? 1 : ((f > 0.999f) ? 2 : 0);
    }
  }
}

// im2col + per-tensor activation quant to u8 (needs hdr[0] from prepA)
__global__ void k_inputq(const float* __restrict__ x, const uint32_t* __restrict__ hdr, uint8_t* __restrict__ iq){
  FPOFF
  int r = blockIdx.x, t = threadIdx.x;
  float a_scale = fmaxf(decf(hdr[0]), 1e-8f) / 127.0f;
  int n = r >> 10, hw = r & 1023, oh = hw >> 5, ow = hw & 31;
  for (int l = t; l < LP; l += 256){
    float val = 0.f;
    if (l < LREAL){
      int c = l / 9, r9 = l - c * 9, ki = r9 / 3, kj = r9 - ki * 3;
      int ih = oh - 1 + ki, iw = ow - 1 + kj;
      if ((unsigned)ih < 32u && (unsigned)iw < 32u)
        val = x[(((n << 6) + c) << 10) + (ih << 5) + iw];
    }
    iq[r * LP + l] = (uint8_t)(int)rintf(val / a_scale);
  }
}

// ---------------- fused prep C: pack | rq (independent; need B and A resp.) ----------------
__global__ void k_prepC(const uint8_t* __restrict__ iq, uint32_t* __restrict__ packB,
                        const int8_t* __restrict__ wq, const uint8_t* __restrict__ cls,
                        float* __restrict__ rq, uint32_t kn0, uint32_t kn1){
  FPOFF
  const int b = blockIdx.x;
  if (b < C_RQ){
    // ---- pack (verbatim) ----
    int gid = b * 256 + threadIdx.x;
    if (gid >= ROWS * 20) return;
    int r = gid / 20, sw = gid - r * 20;
    const uint4* p4 = (const uint4*)(iq + r * LP + sw * 32);
    uint4 a = p4[0], b2 = p4[1];
    uint32_t wds[8] = {a.x, a.y, a.z, a.w, b2.x, b2.y, b2.z, b2.w};
    uint32_t out[NZ];
#pragma unroll
    for (int z = 0; z < NZ; ++z) out[z] = 0u;
#pragma unroll
    for (int tt = 0; tt < 32; ++tt){
      uint32_t byte = (wds[tt >> 2] >> ((tt & 3) * 8)) & 0xFFu;
#pragma unroll
      for (int z = 0; z < NZ; ++z) out[z] |= ((byte >> z) & 1u) << tt;
    }
#pragma unroll
    for (int z = 0; z < NZ; ++z) packB[(z * ROWS + r) * 20 + sw] = out[z];
  } else {
    // ---- rq (verbatim; RNG flat index and store layout unchanged) ----
    int i = (b - C_RQ) * 256 + threadIdx.x;
    if (i >= NNTOT) return;
    U2 rr = threefry(kn0, kn1, 0u, (uint32_t)i);
    uint32_t bits = rr.x ^ rr.y;
    int j = i & 127;
    int t = i >> 7;
    int s = t % 5;
    int t2 = t / 5;
    int o = t2 & 127;
    int t3 = t2 >> 7;
    int k = t3 % 3;
    int z = t3 / 3;
    float f = u2f(bits);
    float u = fmaxf(-0x1.fffffep-1f, f * 2.0f + (-0x1.fffffep-1f));
    float nv = (0x1.6a09e6p+0f * xla_erfinv(u)) * 0.05f;
    int wv = (int)wq[o * LP + s * SUB + j];
    int r0 = wv % 4;  int x1 = (wv - r0) / 4;
    int r1 = x1 % 4;  int x2 = (x1 - r1) / 4;
    int r2 = x2 % 4;
    int rem = (k == 0) ? r0 : ((k == 1) ? r1 : r2);
    float remf = (float)rem;
    float v = remf + remf * nv;
    int c = cls[((k * OC + o) * NS + s) * SUB + j];
    if (c == 1) v = 0.1f;
    else if (c == 2) v = (v > 0.f) ? 1.f : ((v < 0.f) ? -1.f : 0.f);
    rq[(((z * NK + k) * NS + s) * SUB + j) * OC + o] = v;
  }
}

// Fused per-z kernel.  bz<15: r13 mm body for (k=bz/5, s=bz%5); ONLY change
// vs r18 is the partial STORE layout -> [s][o][r] (lane = r consecutive =>
// coalesced 256B/wave dword stores; r18's [s][r][o] scattered 32B chunks at
// 512B stride throttled the dispatch to ~1.15 TB/s HBM).  bz>=15: quantz
// for z-1 with o-major e mapping (o = e>>13, r = e&8191) so partPrev reads
// are block-uniform-o, lane-consecutive-r — coalesced.  outacc is keyed by
// the same o-major e in ALL uses (consistent); no FP op changes anywhere.
__global__ __launch_bounds__(256) void k_mmq(
    const float* __restrict__ rq_z, const uint32_t* __restrict__ packB_z,
    float* __restrict__ partCur, const float* __restrict__ partPrev,
    const float* __restrict__ wscale, uint32_t* __restrict__ hdr,
    float* __restrict__ outacc, float* __restrict__ out,
    const float* __restrict__ bias, int z)
{
  FPOFF
  const int bz = blockIdx.z;
  if (bz < 15){
    // ---------------- mm body ----------------
    __shared__ float lrq[128 * 32];   // [j][32-o band]  16 KB
    __shared__ float red[8];
    const int tid  = threadIdx.x;
    const int wave = tid >> 6;
    const int lane = tid & 63;
    const int k    = bz / 5;
    const int s    = bz - k * 5;
    const int slot = z * NK + k;
    const float* rq_slice = rq_z + (size_t)k * (NS * SUB * OC);
    float* partial = partCur + (size_t)k * PARTSZ;   // [s][o][r]
    const int r0   = blockIdx.x * 128 + lane;   // rows r0 and r0+64
    const int OB   = blockIdx.y * 32;
    const int o0   = OB + wave * 8;

    // stage rq[s][*][32-o band] -> LDS (4096 floats, 4 float4/thread)
    {
      const float* gsrc = rq_slice + (size_t)s * SUB * OC + OB;
#pragma unroll
      for (int it = 0; it < 4; ++it){
        const int f = it * 256 + tid;       // 0..1023
        const int j = f >> 3, q = f & 7;    // 8 float4 per j-row
        const float4 v = *(const float4*)(gsrc + (size_t)j * OC + q * 4);
        *(float4*)&lrq[j * 32 + q * 4] = v;
      }
    }

    // per-lane bit words for the two rows (packB row stride 80 B, 16B aligned)
    const uint4 bwa4 = *(const uint4*)(packB_z + (size_t)r0 * 20 + s * 4);
    const uint4 bwb4 = *(const uint4*)(packB_z + (size_t)(r0 + 64) * 20 + s * 4);
    const uint32_t bwa[4] = {bwa4.x, bwa4.y, bwa4.z, bwa4.w};
    const uint32_t bwb[4] = {bwb4.x, bwb4.y, bwb4.z, bwb4.w};

    __syncthreads();

    float acc0[8], acc1[8];
#pragma unroll
    for (int i = 0; i < 8; ++i){ acc0[i] = 0.f; acc1[i] = 0.f; }

#pragma unroll
    for (int w = 0; w < 4; ++w){
      const uint32_t ba = bwa[w], bb = bwb[w];
#pragma unroll
      for (int jj = 0; jj < 32; ++jj){
        const int mska = ((int)(ba << (31 - jj))) >> 31;
        const int mskb = ((int)(bb << (31 - jj))) >> 31;
        const float bfa = __uint_as_float((uint32_t)mska & 0x3F800000u);
        const float bfb = __uint_as_float((uint32_t)mskb & 0x3F800000u);
        const float* lp = &lrq[(w * 32 + jj) * 32 + wave * 8];  // uniform -> 2x ds_read_b128
#pragma unroll
        for (int i = 0; i < 8; ++i){
          const float rv = lp[i];
          acc0[i] = __builtin_fmaf(rv, bfa, acc0[i]);           // j-ascending chains
          acc1[i] = __builtin_fmaf(rv, bfb, acc1[i]);
        }
      }
    }

    // store: [s][o][r] layout — lane-consecutive r => coalesced dword stores
    {
      float* pb = partial + (size_t)(s * OC + o0) * ROWS + r0;
#pragma unroll
      for (int i = 0; i < 8; ++i){
        pb[(size_t)i * ROWS]      = acc0[i];
        pb[(size_t)i * ROWS + 64] = acc1[i];
      }
    }

    // block min/max -> slot atomics (order-free exact)
    float mn = acc0[0], mx = acc0[0];
#pragma unroll
    for (int i = 1; i < 8; ++i){ mn = fminf(mn, acc0[i]); mx = fmaxf(mx, acc0[i]); }
#pragma unroll
    for (int i = 0; i < 8; ++i){ mn = fminf(mn, acc1[i]); mx = fmaxf(mx, acc1[i]); }
    for (int off = 32; off; off >>= 1){
      mn = fminf(mn, __shfl_down(mn, off));
      mx = fmaxf(mx, __shfl_down(mx, off));
    }
    if (lane == 0){ red[wave] = mn; red[4 + wave] = mx; }
    __syncthreads();
    if (tid == 0){
      mn = fminf(fminf(red[0], red[1]), fminf(red[2], red[3]));
      mx = fmaxf(fmaxf(red[4], red[5]), fmaxf(red[6], red[7]));
      atomicMin(&hdr[8 + slot], encf(mn));
      atomicMax(&hdr[32 + slot], encf(mx));
    }
  } else {
    // ---------------- quantz body for z-1 (o-major e; byte-identical math) ----------------
    const int zP = z - 1;
    const int qid = (bz - 15) * 256 + blockIdx.y * 64 + blockIdx.x;  // 0..4095
    const int e = qid * 256 + threadIdx.x;
    const int o = e >> 13, r = e & 8191;     // o-major: coalesced [s][o][r] reads
    float pqk[NK];
#pragma unroll
    for (int k = 0; k < NK; ++k){
      const float* part = partPrev + (size_t)k * PARTSZ;
      float mn = decf(hdr[8 + zP * NK + k]);
      float mx = decf(hdr[32 + zP * NK + k]);
      float step = (mx - mn) * 0.03125f;
      if (!(step > 0.f)) step = 1.0f;
      float pq = 0.f;
#pragma unroll
      for (int s = 0; s < NS; ++s){
        float v = part[(size_t)(s * OC + o) * ROWS + r];
        float fidx = floorf((v - mn) / step);
        fidx = fminf(fmaxf(fidx, 0.f), 31.f);
        float qv = fidx * step + mn;
        pq = pq + qv * wscale[s * OC + o];
      }
      pqk[k] = pq;
    }
    float outD = pqk[0] + pqk[1] * 4.0f;
    float tt = outD + pqk[2] * 16.0f;
    float a_scale = fmaxf(decf(hdr[0]), 1e-8f) / 127.0f;
    float contrib = (tt * (float)(1 << zP)) * a_scale;
    if (zP == 0) outacc[e] = contrib;
    else outacc[e] = outacc[e] + contrib;   // zP <= 5 here; out-write is the tail kernel
  }
}

// ADC quant for all three k's of one z (tail use: z=6 writes out + bias).
// Same o-major e mapping as the fused quant planes (outacc consistency).
__global__ void k_quantz(const float* __restrict__ p0, const float* __restrict__ p1,
                         const float* __restrict__ p2, const float* __restrict__ wscale,
                         const uint32_t* __restrict__ hdr, float* __restrict__ outacc,
                         float* __restrict__ out, const float* __restrict__ bias, int z){
  FPOFF
  int e = blockIdx.x * 256 + threadIdx.x;   // exactly ROWS*OC threads
  int o = e >> 13, r = e & 8191;            // o-major
  float pqk[NK];
#pragma unroll
  for (int k = 0; k < NK; ++k){
    const float* part = (k == 0) ? p0 : ((k == 1) ? p1 : p2);
    float mn = decf(hdr[8 + z * NK + k]);
    float mx = decf(hdr[32 + z * NK + k]);
    float step = (mx - mn) * 0.03125f;
    if (!(step > 0.f)) step = 1.0f;
    float pq = 0.f;
#pragma unroll
    for (int s = 0; s < NS; ++s){
      float v = part[(size_t)(s * OC + o) * ROWS + r];
      float fidx = floorf((v - mn) / step);
      fidx = fminf(fmaxf(fidx, 0.f), 31.f);
      float qv = fidx * step + mn;
      pq = pq + qv * wscale[s * OC + o];
    }
    pqk[k] = pq;
  }
  float outD = pqk[0] + pqk[1] * 4.0f;
  float tt = outD + pqk[2] * 16.0f;
  float a_scale = fmaxf(decf(hdr[0]), 1e-8f) / 127.0f;
  float contrib = (tt * (float)(1 << z)) * a_scale;
  if (z == 0) outacc[e] = contrib;
  else if (z < NZ - 1) outacc[e] = outacc[e] + contrib;
  else {
    float res = outacc[e] + contrib;
    int n = r >> 10, hw = r & 1023;
    out[(((n << 7) + o) << 10) + hw] = res + bias[o];   // hw lane-consecutive
  }
}

// ---------------- host ----------------
extern "C" void kernel_launch(void* const* d_in, const int* in_sizes, int n_in,
                              void* d_out, int out_size, void* d_ws, size_t ws_size,
                              hipStream_t stream){
  const float* x    = (const float*)d_in[0];
  const float* wt   = (const float*)d_in[1];
  const float* bias = (const float*)d_in[2];
  float* out = (float*)d_out;
  char* ws = (char*)d_ws;
  uint32_t* hdr    = (uint32_t*)(ws + OFF_HDR);
  float*    wscale = (float*)(ws + OFF_WSCALE);
  int8_t*   wq     = (int8_t*)(ws + OFF_WQ);
  uint8_t*  cls    = (uint8_t*)(ws + OFF_CLS);
  uint8_t*  iq     = (uint8_t*)(ws + OFF_INPUTQ);
  uint32_t* packB  = (uint32_t*)(ws + OFF_PACKB);
  float*    rq     = (float*)(ws + OFF_RQ);
  float*    parts  = (float*)(ws + OFF_PARTS);   // [6][PARTSZ]
  float*    outacc = (float*)(ws + OFF_OUTACC);

  // jax.random.key(42) -> (0,42); partitionable (fold-like) split:
  // kmask = threefry(key,(0,0)); knoise = threefry(key,(0,1))
  U2 p0 = threefry(0u, 42u, 0u, 0u);
  U2 p1 = threefry(0u, 42u, 0u, 1u);
  uint32_t km0 = p0.x, km1 = p0.y, kn0 = p1.x, kn1 = p1.y;

  hipLaunchKernelGGL(k_init,   dim3(1),    dim3(64),  0, stream, hdr);
  hipLaunchKernelGGL(k_prepA,  dim3(A_NB), dim3(256), 0, stream, x, wt, hdr, wscale, wq, cls, km0, km1);
  hipLaunchKernelGGL(k_inputq, dim3(8192), dim3(256), 0, stream, x, hdr, iq);
  hipLaunchKernelGGL(k_prepC,  dim3(C_NB), dim3(256), 0, stream, iq, packB, wq, cls, rq, kn0, kn1);

  for (int z = 0; z < NZ; ++z){
    float*       cur  = parts + (size_t)((z & 1) ? 3 : 0) * PARTSZ;
    const float* prev = parts + (size_t)((z & 1) ? 0 : 3) * PARTSZ;
    const float* rqz  = rq + (size_t)z * NK * NS * SUB * OC;
    const uint32_t* pbz = packB + (size_t)z * ROWS * 20;
    dim3 grid(64, 4, (z == 0) ? 15 : 31);   // 15 mm planes (+16 quantz planes)
    hipLaunchKernelGGL(k_mmq, grid, dim3(256), 0, stream,
                       rqz, pbz, cur, prev, wscale, hdr, outacc, out, bias, z);
  }
  // tail quant for z=6 (cur of z=6 is the A triple: offset 0)
  hipLaunchKernelGGL(k_quantz, dim3(4096), dim3(256), 0, stream,
                     parts, parts + PARTSZ, parts + 2 * (size_t)PARTSZ,
                     wscale, hdr, outacc, out, bias, 6);
}

// Round 20
// 584.711 us; speedup vs baseline: 1.0513x; 1.0513x over previous
//
#include <hip/hip_runtime.h>
#include <stdint.h>

#define FPOFF _Pragma("clang fp contract(off)")

// ---------------- problem sizes ----------------
#define ROWS 8192      // N*Ho*Wo = 8*32*32
#define OC 128
#define NS 5           // subarrays
#define SUB 128
#define LP 640         // NS*SUB (padded L)
#define LREAL 576      // C*kh*kw = 64*9
#define NZ 7           // activation bits
#define NK 3           // weight cells
#define NSLOT 21
#define NPTOT 245760   // 3*128*5*128   probs element count
#define NNTOT 1720320  // 7*3*128*5*128 noise element count
#define PARTSZ 5242880 // NS*ROWS*OC floats (one partial buffer)

// prep-A plane bases (1D grid): [0,128)=xmax, [128,288)=wq(160), [288,1248)=cls
// (init is a SEPARATE launch: its plain hdr stores must be ordered before
//  xmax's atomicMax on hdr[0] — fusing them raced across graph replays, r17)
#define A_WQ   128
#define A_CLS  288
#define A_NB   1248
// prep-C plane bases: [0,640)=pack, [640,7360)=rq
#define C_RQ   640
#define C_NB   7360

// ---------------- ws layout (bytes) ----------------
#define OFF_HDR      0u          // u32[64]: [0]=xmax_enc, pmin[21]@idx8, pmax[21]@idx32
#define OFF_WSCALE   256u        // f32 [NS][OC]
#define OFF_WQ       4096u       // i8  [OC][LP]
#define OFF_CLS      86016u      // u8  [NK][OC][NS][SUB]
#define OFF_INPUTQ   331776u     // u8  [ROWS][LP]
#define OFF_PACKB    5574656u    // u32 [NZ][ROWS][NS][4]
#define OFF_RQ       10162176u   // f32 [NZ][NK][NS][SUB][OC]
#define OFF_PARTS    17043456u   // f32 [6][PARTSZ]  (A=0..2 z even, B=3..5 z odd; 126 MB)
#define OFF_OUTACC   142872576u  // f32 [ROWS][OC]   (ends ~147 MB < 256 MB)

struct U2 { uint32_t x, y; };

__host__ __device__ static inline uint32_t rotl32(uint32_t v, int d){ return (v << d) | (v >> (32 - d)); }

// JAX threefry2x32: 20 rounds, injection every 4. keys (k0,k1), counter (c0,c1).
__host__ __device__ static inline U2 threefry(uint32_t k0, uint32_t k1, uint32_t c0, uint32_t c1){
  uint32_t ks2 = k0 ^ k1 ^ 0x1BD11BDAu;
  uint32_t x0 = c0 + k0, x1 = c1 + k1;
#define TFR(r) { x0 += x1; x1 = rotl32(x1, r); x1 ^= x0; }
  TFR(13) TFR(15) TFR(26) TFR(6)  x0 += k1;  x1 += ks2 + 1u;
  TFR(17) TFR(29) TFR(16) TFR(24) x0 += ks2; x1 += k0 + 2u;
  TFR(13) TFR(15) TFR(26) TFR(6)  x0 += k0;  x1 += k1 + 3u;
  TFR(17) TFR(29) TFR(16) TFR(24) x0 += k1;  x1 += ks2 + 4u;
  TFR(13) TFR(15) TFR(26) TFR(6)  x0 += ks2; x1 += k0 + 5u;
#undef TFR
  U2 r; r.x = x0; r.y = x1; return r;
}

__device__ static inline float u2f(uint32_t b){
  // JAX uniform [0,1): bitcast((bits>>9)|0x3f800000) - 1
  return __uint_as_float((b >> 9) | 0x3F800000u) - 1.0f;
}

// order-preserving float<->uint encode for atomic min/max
__device__ static inline uint32_t encf(float f){
  uint32_t u = __float_as_uint(f);
  return (u & 0x80000000u) ? ~u : (u | 0x80000000u);
}
__device__ static inline float decf(uint32_t e){
  return (e & 0x80000000u) ? __uint_as_float(e & 0x7FFFFFFFu) : __uint_as_float(~e);
}

// XLA/chlo erf_inv f32 (Giles). log1p/sqrt via f64 for correctly-rounded f32.
__device__ static inline float xla_erfinv(float x){
  FPOFF
  float m = x * x;
  float w = -(float)log1p((double)(-m));
  float p;
  if (w < 5.0f){
    w = w - 2.5f;
    p = 2.81022636e-08f;
    p = 3.43273939e-07f  + p * w;
    p = -3.5233877e-06f  + p * w;
    p = -4.39150654e-06f + p * w;
    p = 0.00021858087f   + p * w;
    p = -0.00125372503f  + p * w;
    p = -0.00417768164f  + p * w;
    p = 0.246640727f     + p * w;
    p = 1.50140941f      + p * w;
  } else {
    w = (float)sqrt((double)w) - 3.0f;
    p = -0.000200214257f;
    p = 0.000100950558f  + p * w;
    p = 0.00134934322f   + p * w;
    p = -0.00367342844f  + p * w;
    p = 0.00573950773f   + p * w;
    p = -0.0076224613f   + p * w;
    p = 0.00943887047f   + p * w;
    p = 1.00167406f      + p * w;
    p = 2.83297682f      + p * w;
  }
  return p * x;
}

// ---------------- kernels ----------------

// separate launch: must complete before prepA's xmax atomics touch hdr[0]
__global__ void k_init(uint32_t* hdr){
  int t = threadIdx.x;
  if (t == 0) hdr[0] = 0u;
  if (t < NSLOT){ hdr[8 + t] = 0xFFFFFFFFu; hdr[32 + t] = 0u; }
}

// ---------------- fused prep A: xmax | wq | cls ----------------
// All three are mutually independent; disjoint 1D block ranges; bodies verbatim.
__global__ void k_prepA(const float* __restrict__ x, const float* __restrict__ wt,
                        uint32_t* __restrict__ hdr, float* __restrict__ wscale,
                        int8_t* __restrict__ wq, uint8_t* __restrict__ cls,
                        uint32_t km0, uint32_t km1){
  FPOFF
  __shared__ float red[4];
  const int b = blockIdx.x;
  const int t = threadIdx.x;
  if (b < A_WQ){
    // ---- xmax block (verbatim) ----
    const float4* x4 = (const float4*)x;
    int base = b * 1024 + t;
    float m = 0.0f;
#pragma unroll
    for (int i = 0; i < 4; ++i){
      float4 v = x4[base + i * 256];
      m = fmaxf(m, fmaxf(fmaxf(v.x, v.y), fmaxf(v.z, v.w)));
    }
    for (int off = 32; off; off >>= 1) m = fmaxf(m, __shfl_down(m, off));
    if ((t & 63) == 0) red[t >> 6] = m;
    __syncthreads();
    if (t == 0){
      m = fmaxf(fmaxf(red[0], red[1]), fmaxf(red[2], red[3]));
      atomicMax(&hdr[0], encf(m));
    }
  } else if (b < A_CLS){
    // ---- wq: 4 (s,o) pairs per block, one per wave (shuffles are wave-local) ----
    const int p = (b - A_WQ) * 4 + (t >> 6);   // 0..639
    const int s = p >> 7, o = p & 127;
    const int lane = t & 63;
    int l0 = s * SUB + lane, l1 = l0 + 64;
    float w0 = (l0 < LREAL) ? wt[o * LREAL + l0] : 0.f;
    float w1 = (l1 < LREAL) ? wt[o * LREAL + l1] : 0.f;
    float m = fmaxf(fabsf(w0), fabsf(w1));
    for (int off = 32; off; off >>= 1) m = fmaxf(m, __shfl_down(m, off));
    m = __shfl(m, 0);
    float ws = fmaxf(m, 1e-8f) / 127.0f;
    if (lane == 0) wscale[s * OC + o] = ws;
    wq[o * LP + l0] = (int8_t)(int)rintf(w0 / ws);
    wq[o * LP + l1] = (int8_t)(int)rintf(w1 / ws);
  } else {
    // ---- cls (verbatim) ----
    int i = (b - A_CLS) * 256 + t;
    if (i < NPTOT){
      U2 r = threefry(km0, km1, 0u, (uint32_t)i);
      float f = u2f(r.x ^ r.y);
      cls[i] = (f < 0.001f) ? 1 : ((f > 0.999f) ? 2 : 0);
    }
  }
}

// im2col + per-tensor activation quant to u8 (needs hdr[0] from prepA)
__global__ void k_inputq(const float* __restrict__ x, const uint32_t* __restrict__ hdr, uint8_t* __restrict__ iq){
  FPOFF
  int r = blockIdx.x, t = threadIdx.x;
  float a_scale = fmaxf(decf(hdr[0]), 1e-8f) / 127.0f;
  int n = r >> 10, hw = r & 1023, oh = hw >> 5, ow = hw & 31;
  for (int l = t; l < LP; l += 256){
    float val = 0.f;
    if (l < LREAL){
      int c = l / 9, r9 = l - c * 9, ki = r9 / 3, kj = r9 - ki * 3;
      int ih = oh - 1 + ki, iw = ow - 1 + kj;
      if ((unsigned)ih < 32u && (unsigned)iw < 32u)
        val = x[(((n << 6) + c) << 10) + (ih << 5) + iw];
    }
    iq[r * LP + l] = (uint8_t)(int)rintf(val / a_scale);
  }
}

// ---------------- fused prep C: pack | rq (independent; need B and A resp.) ----------------
__global__ void k_prepC(const uint8_t* __restrict__ iq, uint32_t* __restrict__ packB,
                        const int8_t* __restrict__ wq, const uint8_t* __restrict__ cls,
                        float* __restrict__ rq, uint32_t kn0, uint32_t kn1){
  FPOFF
  const int b = blockIdx.x;
  if (b < C_RQ){
    // ---- pack (verbatim) ----
    int gid = b * 256 + threadIdx.x;
    if (gid >= ROWS * 20) return;
    int r = gid / 20, sw = gid - r * 20;
    const uint4* p4 = (const uint4*)(iq + r * LP + sw * 32);
    uint4 a = p4[0], b2 = p4[1];
    uint32_t wds[8] = {a.x, a.y, a.z, a.w, b2.x, b2.y, b2.z, b2.w};
    uint32_t out[NZ];
#pragma unroll
    for (int z = 0; z < NZ; ++z) out[z] = 0u;
#pragma unroll
    for (int tt = 0; tt < 32; ++tt){
      uint32_t byte = (wds[tt >> 2] >> ((tt & 3) * 8)) & 0xFFu;
#pragma unroll
      for (int z = 0; z < NZ; ++z) out[z] |= ((byte >> z) & 1u) << tt;
    }
#pragma unroll
    for (int z = 0; z < NZ; ++z) packB[(z * ROWS + r) * 20 + sw] = out[z];
  } else {
    // ---- rq (verbatim; RNG flat index and store layout unchanged) ----
    int i = (b - C_RQ) * 256 + threadIdx.x;
    if (i >= NNTOT) return;
    U2 rr = threefry(kn0, kn1, 0u, (uint32_t)i);
    uint32_t bits = rr.x ^ rr.y;
    int j = i & 127;
    int t = i >> 7;
    int s = t % 5;
    int t2 = t / 5;
    int o = t2 & 127;
    int t3 = t2 >> 7;
    int k = t3 % 3;
    int z = t3 / 3;
    float f = u2f(bits);
    float u = fmaxf(-0x1.fffffep-1f, f * 2.0f + (-0x1.fffffep-1f));
    float nv = (0x1.6a09e6p+0f * xla_erfinv(u)) * 0.05f;
    int wv = (int)wq[o * LP + s * SUB + j];
    int r0 = wv % 4;  int x1 = (wv - r0) / 4;
    int r1 = x1 % 4;  int x2 = (x1 - r1) / 4;
    int r2 = x2 % 4;
    int rem = (k == 0) ? r0 : ((k == 1) ? r1 : r2);
    float remf = (float)rem;
    float v = remf + remf * nv;
    int c = cls[((k * OC + o) * NS + s) * SUB + j];
    if (c == 1) v = 0.1f;
    else if (c == 2) v = (v > 0.f) ? 1.f : ((v < 0.f) ? -1.f : 0.f);
    rq[(((z * NK + k) * NS + s) * SUB + j) * OC + o] = v;
  }
}

// Fused per-z kernel (r15 structure, best-measured).  bz<15: r13's mm body
// for (k=bz/5, s=bz%5) of this z (rpl=2, 4 waves x 8-o tiles, LDS 16 KB,
// bit-exact j-ascending chains).  bz>=15: quantz body for z-1
// (byte-identical op order), reading the ping-pong'd previous partial
// triple — HBM reads overlap mm compute.
__global__ __launch_bounds__(256) void k_mmq(
    const float* __restrict__ rq_z, const uint32_t* __restrict__ packB_z,
    float* __restrict__ partCur, const float* __restrict__ partPrev,
    const float* __restrict__ wscale, uint32_t* __restrict__ hdr,
    float* __restrict__ outacc, float* __restrict__ out,
    const float* __restrict__ bias, int z)
{
  FPOFF
  const int bz = blockIdx.z;
  if (bz < 15){
    // ---------------- mm body (r13 verbatim) ----------------
    __shared__ float lrq[128 * 32];   // [j][32-o band]  16 KB
    __shared__ float red[8];
    const int tid  = threadIdx.x;
    const int wave = tid >> 6;
    const int lane = tid & 63;
    const int k    = bz / 5;
    const int s    = bz - k * 5;
    const int slot = z * NK + k;
    const float* rq_slice = rq_z + (size_t)k * (NS * SUB * OC);
    float* partial = partCur + (size_t)k * PARTSZ;
    const int r0   = blockIdx.x * 128 + lane;   // rows r0 and r0+64
    const int OB   = blockIdx.y * 32;
    const int o0   = OB + wave * 8;

    // stage rq[s][*][32-o band] -> LDS (4096 floats, 4 float4/thread)
    {
      const float* gsrc = rq_slice + (size_t)s * SUB * OC + OB;
#pragma unroll
      for (int it = 0; it < 4; ++it){
        const int f = it * 256 + tid;       // 0..1023
        const int j = f >> 3, q = f & 7;    // 8 float4 per j-row
        const float4 v = *(const float4*)(gsrc + (size_t)j * OC + q * 4);
        *(float4*)&lrq[j * 32 + q * 4] = v;
      }
    }

    // per-lane bit words for the two rows (packB row stride 80 B, 16B aligned)
    const uint4 bwa4 = *(const uint4*)(packB_z + (size_t)r0 * 20 + s * 4);
    const uint4 bwb4 = *(const uint4*)(packB_z + (size_t)(r0 + 64) * 20 + s * 4);
    const uint32_t bwa[4] = {bwa4.x, bwa4.y, bwa4.z, bwa4.w};
    const uint32_t bwb[4] = {bwb4.x, bwb4.y, bwb4.z, bwb4.w};

    __syncthreads();

    float acc0[8], acc1[8];
#pragma unroll
    for (int i = 0; i < 8; ++i){ acc0[i] = 0.f; acc1[i] = 0.f; }

#pragma unroll
    for (int w = 0; w < 4; ++w){
      const uint32_t ba = bwa[w], bb = bwb[w];
#pragma unroll
      for (int jj = 0; jj < 32; ++jj){
        const int mska = ((int)(ba << (31 - jj))) >> 31;
        const int mskb = ((int)(bb << (31 - jj))) >> 31;
        const float bfa = __uint_as_float((uint32_t)mska & 0x3F800000u);
        const float bfb = __uint_as_float((uint32_t)mskb & 0x3F800000u);
        const float* lp = &lrq[(w * 32 + jj) * 32 + wave * 8];  // uniform -> 2x ds_read_b128
#pragma unroll
        for (int i = 0; i < 8; ++i){
          const float rv = lp[i];
          acc0[i] = __builtin_fmaf(rv, bfa, acc0[i]);           // j-ascending chains
          acc1[i] = __builtin_fmaf(rv, bfb, acc1[i]);
        }
      }
    }

    // store: 8 consecutive o per lane per row (2x float4 each)
    {
      float4* p0 = (float4*)(partial + (size_t)(s * ROWS + r0) * OC + o0);
      p0[0] = make_float4(acc0[0], acc0[1], acc0[2], acc0[3]);
      p0[1] = make_float4(acc0[4], acc0[5], acc0[6], acc0[7]);
      float4* p1 = (float4*)(partial + (size_t)(s * ROWS + r0 + 64) * OC + o0);
      p1[0] = make_float4(acc1[0], acc1[1], acc1[2], acc1[3]);
      p1[1] = make_float4(acc1[4], acc1[5], acc1[6], acc1[7]);
    }

    // block min/max -> slot atomics (order-free exact)
    float mn = acc0[0], mx = acc0[0];
#pragma unroll
    for (int i = 1; i < 8; ++i){ mn = fminf(mn, acc0[i]); mx = fmaxf(mx, acc0[i]); }
#pragma unroll
    for (int i = 0; i < 8; ++i){ mn = fminf(mn, acc1[i]); mx = fmaxf(mx, acc1[i]); }
    for (int off = 32; off; off >>= 1){
      mn = fminf(mn, __shfl_down(mn, off));
      mx = fmaxf(mx, __shfl_down(mx, off));
    }
    if (lane == 0){ red[wave] = mn; red[4 + wave] = mx; }
    __syncthreads();
    if (tid == 0){
      mn = fminf(fminf(red[0], red[1]), fminf(red[2], red[3]));
      mx = fmaxf(fmaxf(red[4], red[5]), fmaxf(red[6], red[7]));
      atomicMin(&hdr[8 + slot], encf(mn));
      atomicMax(&hdr[32 + slot], encf(mx));
    }
  } else {
    // ---------------- quantz body for z-1 (byte-identical math) ----------------
    const int zP = z - 1;
    const int qid = (bz - 15) * 256 + blockIdx.y * 64 + blockIdx.x;  // 0..4095
    const int e = qid * 256 + threadIdx.x;
    const int r = e >> 7, o = e & 127;
    float pqk[NK];
#pragma unroll
    for (int k = 0; k < NK; ++k){
      const float* part = partPrev + (size_t)k * PARTSZ;
      float mn = decf(hdr[8 + zP * NK + k]);
      float mx = decf(hdr[32 + zP * NK + k]);
      float step = (mx - mn) * 0.03125f;
      if (!(step > 0.f)) step = 1.0f;
      float pq = 0.f;
#pragma unroll
      for (int s = 0; s < NS; ++s){
        float v = part[(size_t)(s * ROWS + r) * OC + o];
        float fidx = floorf((v - mn) / step);
        fidx = fminf(fmaxf(fidx, 0.f), 31.f);
        float qv = fidx * step + mn;
        pq = pq + qv * wscale[s * OC + o];
      }
      pqk[k] = pq;
    }
    float outD = pqk[0] + pqk[1] * 4.0f;
    float tt = outD + pqk[2] * 16.0f;
    float a_scale = fmaxf(decf(hdr[0]), 1e-8f) / 127.0f;
    float contrib = (tt * (float)(1 << zP)) * a_scale;
    if (zP == 0) outacc[e] = contrib;
    else outacc[e] = outacc[e] + contrib;   // zP <= 5 here; out-write is the tail kernel
  }
}

// ADC quant for all three k's of one z (tail use: z=6 writes out + bias).
__global__ void k_quantz(const float* __restrict__ p0, const float* __restrict__ p1,
                         const float* __restrict__ p2, const float* __restrict__ wscale,
                         const uint32_t* __restrict__ hdr, float* __restrict__ outacc,
                         float* __restrict__ out, const float* __restrict__ bias, int z){
  FPOFF
  int e = blockIdx.x * 256 + threadIdx.x;   // exactly ROWS*OC threads
  int r = e >> 7, o = e & 127;
  float pqk[NK];
#pragma unroll
  for (int k = 0; k < NK; ++k){
    const float* part = (k == 0) ? p0 : ((k == 1) ? p1 : p2);
    float mn = decf(hdr[8 + z * NK + k]);
    float mx = decf(hdr[32 + z * NK + k]);
    float step = (mx - mn) * 0.03125f;
    if (!(step > 0.f)) step = 1.0f;
    float pq = 0.f;
#pragma unroll
    for (int s = 0; s < NS; ++s){
      float v = part[(size_t)(s * ROWS + r) * OC + o];
      float fidx = floorf((v - mn) / step);
      fidx = fminf(fmaxf(fidx, 0.f), 31.f);
      float qv = fidx * step + mn;
      pq = pq + qv * wscale[s * OC + o];
    }
    pqk[k] = pq;
  }
  float outD = pqk[0] + pqk[1] * 4.0f;
  float tt = outD + pqk[2] * 16.0f;
  float a_scale = fmaxf(decf(hdr[0]), 1e-8f) / 127.0f;
  float contrib = (tt * (float)(1 << z)) * a_scale;
  if (z == 0) outacc[e] = contrib;
  else if (z < NZ - 1) outacc[e] = outacc[e] + contrib;
  else {
    float res = outacc[e] + contrib;
    int n = r >> 10, hw = r & 1023;
    out[(((n << 7) + o) << 10) + hw] = res + bias[o];
  }
}

// ---------------- host ----------------
extern "C" void kernel_launch(void* const* d_in, const int* in_sizes, int n_in,
                              void* d_out, int out_size, void* d_ws, size_t ws_size,
                              hipStream_t stream){
  const float* x    = (const float*)d_in[0];
  const float* wt   = (const float*)d_in[1];
  const float* bias = (const float*)d_in[2];
  float* out = (float*)d_out;
  char* ws = (char*)d_ws;
  uint32_t* hdr    = (uint32_t*)(ws + OFF_HDR);
  float*    wscale = (float*)(ws + OFF_WSCALE);
  int8_t*   wq     = (int8_t*)(ws + OFF_WQ);
  uint8_t*  cls    = (uint8_t*)(ws + OFF_CLS);
  uint8_t*  iq     = (uint8_t*)(ws + OFF_INPUTQ);
  uint32_t* packB  = (uint32_t*)(ws + OFF_PACKB);
  float*    rq     = (float*)(ws + OFF_RQ);
  float*    parts  = (float*)(ws + OFF_PARTS);   // [6][PARTSZ]
  float*    outacc = (float*)(ws + OFF_OUTACC);

  // jax.random.key(42) -> (0,42); partitionable (fold-like) split:
  // kmask = threefry(key,(0,0)); knoise = threefry(key,(0,1))
  U2 p0 = threefry(0u, 42u, 0u, 0u);
  U2 p1 = threefry(0u, 42u, 0u, 1u);
  uint32_t km0 = p0.x, km1 = p0.y, kn0 = p1.x, kn1 = p1.y;

  hipLaunchKernelGGL(k_init,   dim3(1),    dim3(64),  0, stream, hdr);
  hipLaunchKernelGGL(k_prepA,  dim3(A_NB), dim3(256), 0, stream, x, wt, hdr, wscale, wq, cls, km0, km1);
  hipLaunchKernelGGL(k_inputq, dim3(8192), dim3(256), 0, stream, x, hdr, iq);
  hipLaunchKernelGGL(k_prepC,  dim3(C_NB), dim3(256), 0, stream, iq, packB, wq, cls, rq, kn0, kn1);

  for (int z = 0; z < NZ; ++z){
    float*       cur  = parts + (size_t)((z & 1) ? 3 : 0) * PARTSZ;
    const float* prev = parts + (size_t)((z & 1) ? 0 : 3) * PARTSZ;
    const float* rqz  = rq + (size_t)z * NK * NS * SUB * OC;
    const uint32_t* pbz = packB + (size_t)z * ROWS * 20;
    dim3 grid(64, 4, (z == 0) ? 15 : 31);   // 15 mm planes (+16 quantz planes)
    hipLaunchKernelGGL(k_mmq, grid, dim3(256), 0, stream,
                       rqz, pbz, cur, prev, wscale, hdr, outacc, out, bias, z);
  }
  // tail quant for z=6 (cur of z=6 is the A triple: offset 0)
  hipLaunchKernelGGL(k_quantz, dim3(4096), dim3(256), 0, stream,
                     parts, parts + PARTSZ, parts + 2 * (size_t)PARTSZ,
                     wscale, hdr, outacc, out, bias, 6);
}